// Round 1
// baseline (687.221 us; speedup 1.0000x reference)
//
#include <hip/hip_runtime.h>
#include <hip/hip_bf16.h>
#include <hip/hip_fp16.h>
#include <math.h>

#define NN 100000
#define EE 1600000
#define BB 256
#define NBUCK 391          // ceil(NN/256) coarse buckets (dst>>8)
#define PBLK 384           // blocks per view in bucket pass
#define CH 4167            // edges per block (384*4167 >= EE)
#define TOTB (3 * PBLK)    // total bucket-pass blocks
#define ROWS_PAD 100096    // 782*128
#define EPV (EE + NN)      // entries per view incl self-loops
#define LOG2E 1.442695041f

typedef short bf16x8 __attribute__((ext_vector_type(8)));
typedef float f32x4 __attribute__((ext_vector_type(4)));

__device__ __forceinline__ unsigned short f2bf(float f) {
    __hip_bfloat16 h = __float2bfloat16(f);   // RNE
    return *(unsigned short*)&h;
}
__device__ __forceinline__ unsigned short f2h(float f) {
    __half h = __float2half(f);               // RNE
    return *(unsigned short*)&h;
}
__device__ __forceinline__ float h2f(unsigned short u) {
    __half h = *(__half*)&u;
    return __half2float(h);
}

// ---------------------------------------------------------------- pack W^T to bf16 [n][k]
// which==0 (proj): fold ln_g -> bf16(g[k]*W[k,n])
__global__ __launch_bounds__(256) void pack_wt(const float* __restrict__ W0,
                                               const float* __restrict__ W1,
                                               const float* __restrict__ W2,
                                               const float* __restrict__ W3,
                                               const float* __restrict__ ln_g,
                                               unsigned short* __restrict__ WT) {
    int which = blockIdx.y;
    const float* W = which == 0 ? W0 : which == 1 ? W1 : which == 2 ? W2 : W3;
    int i = blockIdx.x * 256 + threadIdx.x;   // 0..16383
    int n = i >> 7, k = i & 127;
    float v = W[k * 128 + n];
    if (which == 0) v *= ln_g[k];
    WT[which * 16384 + i] = f2bf(v);
}

// ---------------------------------------------------------------- LN affine constants
__global__ __launch_bounds__(128) void ln_consts(const float* __restrict__ W,
                                                 const float* __restrict__ g,
                                                 const float* __restrict__ b,
                                                 float* __restrict__ c12) {
    int n = threadIdx.x;
    float c1 = 0.f, c2 = 0.f;
    for (int k = 0; k < 128; k++) {
        float w = W[k * 128 + n];
        c1 = fmaf(g[k], w, c1);
        c2 = fmaf(b[k], w, c2);
    }
    c12[n] = c1;
    c12[128 + n] = c2;
}

// ================================================================ device bodies

// ---- coarse histogram body (blockHistT layout [bucket][TOTB])
__device__ __forceinline__ void hist_body(int bid, int tid,
                                          const int* __restrict__ e0,
                                          const int* __restrict__ e1,
                                          const int* __restrict__ e2,
                                          int* __restrict__ blockHistT) {
    int v = bid / PBLK, p = bid % PBLK;
    const int* ei = v == 0 ? e0 : v == 1 ? e1 : e2;
    __shared__ int h[NBUCK];
    for (int i = tid; i < NBUCK; i += 256) h[i] = 0;
    __syncthreads();
    int ea = p * CH, ebnd = min(EE, ea + CH);
    int e = ea + tid;
    for (; e + 768 < ebnd; e += 1024) {
        int d0 = ei[EE + e], d1 = ei[EE + e + 256];
        int d2 = ei[EE + e + 512], d3 = ei[EE + e + 768];
        atomicAdd(&h[((unsigned)d0) >> 8], 1);
        atomicAdd(&h[((unsigned)d1) >> 8], 1);
        atomicAdd(&h[((unsigned)d2) >> 8], 1);
        atomicAdd(&h[((unsigned)d3) >> 8], 1);
    }
    for (; e < ebnd; e += 256) atomicAdd(&h[((unsigned)ei[EE + e]) >> 8], 1);
    __syncthreads();
    for (int i = tid; i < NBUCK; i += 256) blockHistT[i * TOTB + bid] = h[i];
}

// ---- proj GEMM body (fused LayerNorm), writes h0 bf16
__device__ __forceinline__ void proj_body(int nb, int tid,
                                          const float* __restrict__ X,
                                          const unsigned short* __restrict__ WT,
                                          const float* __restrict__ c12,
                                          const float* __restrict__ pb,
                                          unsigned short* __restrict__ Out) {
    int w = tid >> 6, lane = tid & 63;
    int ln = lane & 15, oct = lane >> 4;
    int row0 = nb * 128 + w * 32;

    f32x4 acc[2][8];
    #pragma unroll
    for (int i = 0; i < 2; i++)
        #pragma unroll
        for (int j = 0; j < 8; j++) acc[i][j] = (f32x4){0.f, 0.f, 0.f, 0.f};

    const float* X0 = X + (size_t)min(row0 + ln, NN - 1) * 128;
    const float* X1 = X + (size_t)min(row0 + 16 + ln, NN - 1) * 128;
    const bf16x8* Wr = (const bf16x8*)(WT + (size_t)ln * 128);

    float s0 = 0.f, q0 = 0.f, s1 = 0.f, q1 = 0.f;
    #pragma unroll
    for (int kq = 0; kq < 4; kq++) {
        int koff = kq * 4 + oct;
        float4 xa = *(const float4*)(X0 + koff * 8);
        float4 xb = *(const float4*)(X0 + koff * 8 + 4);
        float4 ya = *(const float4*)(X1 + koff * 8);
        float4 yb = *(const float4*)(X1 + koff * 8 + 4);
        s0 += (xa.x + xa.y) + (xa.z + xa.w) + (xb.x + xb.y) + (xb.z + xb.w);
        q0 += xa.x * xa.x + xa.y * xa.y + xa.z * xa.z + xa.w * xa.w
            + xb.x * xb.x + xb.y * xb.y + xb.z * xb.z + xb.w * xb.w;
        s1 += (ya.x + ya.y) + (ya.z + ya.w) + (yb.x + yb.y) + (yb.z + yb.w);
        q1 += ya.x * ya.x + ya.y * ya.y + ya.z * ya.z + ya.w * ya.w
            + yb.x * yb.x + yb.y * yb.y + yb.z * yb.z + yb.w * yb.w;
        bf16x8 a0, a1;
        a0[0] = (short)f2bf(xa.x); a0[1] = (short)f2bf(xa.y); a0[2] = (short)f2bf(xa.z); a0[3] = (short)f2bf(xa.w);
        a0[4] = (short)f2bf(xb.x); a0[5] = (short)f2bf(xb.y); a0[6] = (short)f2bf(xb.z); a0[7] = (short)f2bf(xb.w);
        a1[0] = (short)f2bf(ya.x); a1[1] = (short)f2bf(ya.y); a1[2] = (short)f2bf(ya.z); a1[3] = (short)f2bf(ya.w);
        a1[4] = (short)f2bf(yb.x); a1[5] = (short)f2bf(yb.y); a1[6] = (short)f2bf(yb.z); a1[7] = (short)f2bf(yb.w);
        #pragma unroll
        for (int ct = 0; ct < 8; ct++) {
            bf16x8 bfr = Wr[ct * 16 * 16 + koff];
            acc[0][ct] = __builtin_amdgcn_mfma_f32_16x16x32_bf16(a0, bfr, acc[0][ct], 0, 0, 0);
            acc[1][ct] = __builtin_amdgcn_mfma_f32_16x16x32_bf16(a1, bfr, acc[1][ct], 0, 0, 0);
        }
    }
    #pragma unroll
    for (int m = 16; m < 64; m <<= 1) {
        s0 += __shfl_xor(s0, m); q0 += __shfl_xor(q0, m);
        s1 += __shfl_xor(s1, m); q1 += __shfl_xor(q1, m);
    }
    float mu0 = s0 * (1.0f / 128.0f);
    float rs0 = rsqrtf(q0 * (1.0f / 128.0f) - mu0 * mu0 + 1e-5f);
    float mu1 = s1 * (1.0f / 128.0f);
    float rs1 = rsqrtf(q1 * (1.0f / 128.0f) - mu1 * mu1 + 1e-5f);

    float c1v[8], c2v[8], pbv[8];
    #pragma unroll
    for (int ct = 0; ct < 8; ct++) {
        c1v[ct] = c12[ct * 16 + ln];
        c2v[ct] = c12[128 + ct * 16 + ln];
        pbv[ct] = pb[ct * 16 + ln];
    }
    #pragma unroll
    for (int rt = 0; rt < 2; rt++) {
        #pragma unroll
        for (int r = 0; r < 4; r++) {
            int src = oct * 4 + r;
            float rs_r = __shfl(rt ? rs1 : rs0, src);
            float mu_r = __shfl(rt ? mu1 : mu0, src);
            int row = row0 + rt * 16 + oct * 4 + r;
            #pragma unroll
            for (int ct = 0; ct < 8; ct++) {
                float v = rs_r * acc[rt][ct][r] - rs_r * mu_r * c1v[ct] + c2v[ct] + pbv[ct];
                v = v > 0.f ? v : 0.01f * v;
                Out[(size_t)row * 128 + ct * 16 + ln] = f2bf(v);
            }
        }
    }
}

// ---- coarse scatter body
__device__ __forceinline__ void scatter_body(int bid, int tid,
                                             const int* __restrict__ e0,
                                             const int* __restrict__ e1,
                                             const int* __restrict__ e2,
                                             const int* __restrict__ blockOffT,
                                             unsigned int* __restrict__ pairbuf) {
    int v = bid / PBLK, p = bid % PBLK;
    const int* ei = v == 0 ? e0 : v == 1 ? e1 : e2;
    __shared__ int cur[NBUCK];
    for (int i = tid; i < NBUCK; i += 256) cur[i] = blockOffT[(size_t)i * TOTB + bid];
    __syncthreads();
    int ea = p * CH, ebnd = min(EE, ea + CH);
    unsigned int* pbuf = pairbuf + (size_t)v * EE;
    int e = ea + tid;
    for (; e + 768 < ebnd; e += 1024) {
        unsigned s0 = (unsigned)ei[e],       d0 = (unsigned)ei[EE + e];
        unsigned s1 = (unsigned)ei[e + 256], d1 = (unsigned)ei[EE + e + 256];
        unsigned s2 = (unsigned)ei[e + 512], d2 = (unsigned)ei[EE + e + 512];
        unsigned s3 = (unsigned)ei[e + 768], d3 = (unsigned)ei[EE + e + 768];
        int p0 = atomicAdd(&cur[d0 >> 8], 1);
        int p1 = atomicAdd(&cur[d1 >> 8], 1);
        int p2 = atomicAdd(&cur[d2 >> 8], 1);
        int p3 = atomicAdd(&cur[d3 >> 8], 1);
        pbuf[p0] = (s0 << 8) | (d0 & 255u);
        pbuf[p1] = (s1 << 8) | (d1 & 255u);
        pbuf[p2] = (s2 << 8) | (d2 & 255u);
        pbuf[p3] = (s3 << 8) | (d3 & 255u);
    }
    for (; e < ebnd; e += 256) {
        unsigned s = (unsigned)ei[e], d = (unsigned)ei[EE + e];
        int pos = atomicAdd(&cur[d >> 8], 1);
        pbuf[pos] = (s << 8) | (d & 255u);
    }
}

// ---- view GEMM body (bf16 A in, fp16 xh out, fused att reduction)
__device__ __forceinline__ void view_body(int nb, int tid,
                                          const unsigned short* __restrict__ h0,
                                          const unsigned short* __restrict__ WTv,
                                          const float* __restrict__ asw,
                                          const float* __restrict__ adw,
                                          unsigned short* __restrict__ Out,
                                          float* __restrict__ a_src,
                                          float* __restrict__ a_dst) {
    int w = tid >> 6, lane = tid & 63;
    int ln = lane & 15, oct = lane >> 4;
    int row0 = nb * 128 + w * 32;

    f32x4 acc[2][8];
    #pragma unroll
    for (int i = 0; i < 2; i++)
        #pragma unroll
        for (int j = 0; j < 8; j++) acc[i][j] = (f32x4){0.f, 0.f, 0.f, 0.f};

    const bf16x8* Ar0 = (const bf16x8*)(h0 + (size_t)(row0 + ln) * 128);
    const bf16x8* Ar1 = (const bf16x8*)(h0 + (size_t)(row0 + 16 + ln) * 128);
    const bf16x8* Wr  = (const bf16x8*)(WTv + (size_t)ln * 128);

    #pragma unroll
    for (int kq = 0; kq < 4; kq++) {
        int koff = kq * 4 + oct;
        bf16x8 a0 = Ar0[koff];
        bf16x8 a1 = Ar1[koff];
        #pragma unroll
        for (int ct = 0; ct < 8; ct++) {
            bf16x8 bfr = Wr[ct * 16 * 16 + koff];
            acc[0][ct] = __builtin_amdgcn_mfma_f32_16x16x32_bf16(a0, bfr, acc[0][ct], 0, 0, 0);
            acc[1][ct] = __builtin_amdgcn_mfma_f32_16x16x32_bf16(a1, bfr, acc[1][ct], 0, 0, 0);
        }
    }
    float aswv[8], adwv[8];
    #pragma unroll
    for (int ct = 0; ct < 8; ct++) { aswv[ct] = asw[ct * 16 + ln]; adwv[ct] = adw[ct * 16 + ln]; }

    #pragma unroll
    for (int rt = 0; rt < 2; rt++) {
        #pragma unroll
        for (int r = 0; r < 4; r++) {
            int row = row0 + rt * 16 + oct * 4 + r;
            float sh_[4] = {0.f, 0.f, 0.f, 0.f}, dh_[4] = {0.f, 0.f, 0.f, 0.f};
            #pragma unroll
            for (int ct = 0; ct < 8; ct++) {
                float vv = acc[rt][ct][r];
                Out[(size_t)row * 128 + ct * 16 + ln] = f2h(vv);
                sh_[ct >> 1] = fmaf(vv, aswv[ct], sh_[ct >> 1]);
                dh_[ct >> 1] = fmaf(vv, adwv[ct], dh_[ct >> 1]);
            }
            #pragma unroll
            for (int off = 1; off < 16; off <<= 1) {
                #pragma unroll
                for (int h = 0; h < 4; h++) {
                    sh_[h] += __shfl_xor(sh_[h], off);
                    dh_[h] += __shfl_xor(dh_[h], off);
                }
            }
            if (ln == 0) {
                *(float4*)(a_src + (size_t)row * 4) = make_float4(sh_[0], sh_[1], sh_[2], sh_[3]);
                *(float4*)(a_dst + (size_t)row * 4) = make_float4(dh_[0], dh_[1], dh_[2], dh_[3]);
            }
        }
    }
}

// ================================================================ fat/merged kernels (simple concatenation)
__global__ __launch_bounds__(256) void fat_hist_proj(const int* e0, const int* e1, const int* e2,
                                                     int* blockHistT,
                                                     const float* X, const unsigned short* WT,
                                                     const float* c12, const float* pb,
                                                     unsigned short* h0) {
    if (blockIdx.x < TOTB) hist_body(blockIdx.x, threadIdx.x, e0, e1, e2, blockHistT);
    else proj_body(blockIdx.x - TOTB, threadIdx.x, X, WT, c12, pb, h0);
}

__global__ __launch_bounds__(256) void fat_scatter_view(const int* e0, const int* e1, const int* e2,
                                                        const int* blockOffT, unsigned int* pairbuf,
                                                        const unsigned short* h0, const unsigned short* WT,
                                                        const float* as0, const float* ad0,
                                                        unsigned short* xh, float* a_src, float* a_dst) {
    if (blockIdx.x < TOTB) scatter_body(blockIdx.x, threadIdx.x, e0, e1, e2, blockOffT, pairbuf);
    else view_body(blockIdx.x - TOTB, threadIdx.x, h0, WT + 16384, as0, ad0, xh, a_src, a_dst);
}

__global__ __launch_bounds__(256) void gemm_view(const unsigned short* __restrict__ h0,
                                                 const unsigned short* __restrict__ WTv,
                                                 const float* __restrict__ asw,
                                                 const float* __restrict__ adw,
                                                 unsigned short* __restrict__ Out,
                                                 float* __restrict__ a_src,
                                                 float* __restrict__ a_dst) {
    view_body(blockIdx.x, threadIdx.x, h0, WTv, asw, adw, Out, a_src, a_dst);
}

// ================================================================ CSR small kernels
__global__ __launch_bounds__(256) void csr_bsum(const int* __restrict__ blockHistT,
                                                int* __restrict__ btot) {
    int wid = (blockIdx.x * 256 + threadIdx.x) >> 6;
    int lane = threadIdx.x & 63;
    if (wid >= 3 * NBUCK) return;
    int v = wid / NBUCK, b = wid - v * NBUCK;
    const int* row = blockHistT + (size_t)b * TOTB + v * PBLK;
    int s = 0;
    #pragma unroll
    for (int j = 0; j < 6; j++) s += row[lane * 6 + j];
    #pragma unroll
    for (int m = 1; m < 64; m <<= 1) s += __shfl_xor(s, m);
    if (lane == 0) btot[wid] = s;
}

__global__ __launch_bounds__(512) void csr_scan(const int* __restrict__ btot,
                                                int* __restrict__ ebstart,
                                                int* __restrict__ bstart) {
    int v = blockIdx.x, t = threadIdx.x;
    __shared__ int se[512], ss[512];
    int tot_e = (t < NBUCK) ? btot[v * NBUCK + t] : 0;
    int nval = (t < NBUCK) ? min(256, NN - t * 256) : 0;
    int tot_s = tot_e + nval;
    se[t] = tot_e; ss[t] = tot_s;
    __syncthreads();
    for (int s = 1; s < 512; s <<= 1) {
        int ae = (t >= s) ? se[t - s] : 0;
        int as_ = (t >= s) ? ss[t - s] : 0;
        __syncthreads();
        se[t] += ae; ss[t] += as_;
        __syncthreads();
    }
    if (t < NBUCK) {
        ebstart[v * (NBUCK + 1) + t] = se[t] - tot_e;
        bstart[v * (NBUCK + 1) + t] = ss[t] - tot_s;
    }
    if (t == NBUCK - 1) {
        ebstart[v * (NBUCK + 1) + NBUCK] = se[t];
        bstart[v * (NBUCK + 1) + NBUCK] = ss[t];
    }
}

__global__ __launch_bounds__(256) void csr_boff(const int* __restrict__ blockHistT,
                                                const int* __restrict__ ebstart,
                                                int* __restrict__ blockOffT) {
    int wid = (blockIdx.x * 256 + threadIdx.x) >> 6;
    int lane = threadIdx.x & 63;
    if (wid >= 3 * NBUCK) return;
    int v = wid / NBUCK, b = wid - v * NBUCK;
    const int* row = blockHistT + (size_t)b * TOTB + v * PBLK;
    int* orow = blockOffT + (size_t)b * TOTB + v * PBLK;
    int vals[6], lexcl[6];
    int ls = 0;
    #pragma unroll
    for (int j = 0; j < 6; j++) vals[j] = row[lane * 6 + j];
    #pragma unroll
    for (int j = 0; j < 6; j++) { lexcl[j] = ls; ls += vals[j]; }
    int incl = ls;
    #pragma unroll
    for (int m = 1; m < 64; m <<= 1) {
        int t = __shfl_up(incl, m);
        if (lane >= m) incl += t;
    }
    int wexcl = incl - ls;
    int base = ebstart[v * (NBUCK + 1) + b];
    #pragma unroll
    for (int j = 0; j < 6; j++) orow[lane * 6 + j] = base + wexcl + lexcl[j];
}

__global__ __launch_bounds__(256) void csr_fine(const unsigned int* __restrict__ pairbuf,
                                                const int* __restrict__ btot,
                                                const int* __restrict__ ebstart,
                                                const int* __restrict__ bstart,
                                                int* __restrict__ deg3,
                                                int* __restrict__ start3,
                                                unsigned int* __restrict__ ebuf3) {
    int v = blockIdx.x / NBUCK, b = blockIdx.x - v * NBUCK;
    int cnt   = btot[v * NBUCK + b];
    int pbase = ebstart[v * (NBUCK + 1) + b];
    int obase = bstart[v * (NBUCK + 1) + b];
    const unsigned int* pb = pairbuf + (size_t)v * EE + pbase;
    unsigned int* eb = ebuf3 + (size_t)v * EPV + obase;
    __shared__ int hist[256], scan[256], cur[256];
    int t = threadIdx.x;
    int node = b * 256 + t;
    int valid = (node < NN) ? 1 : 0;
    hist[t] = valid;
    __syncthreads();
    {
        int i = t;
        for (; i + 768 < cnt; i += 1024) {
            unsigned v0 = pb[i], v1 = pb[i + 256], v2 = pb[i + 512], v3 = pb[i + 768];
            atomicAdd(&hist[v0 & 255u], 1);
            atomicAdd(&hist[v1 & 255u], 1);
            atomicAdd(&hist[v2 & 255u], 1);
            atomicAdd(&hist[v3 & 255u], 1);
        }
        for (; i < cnt; i += 256) atomicAdd(&hist[pb[i] & 255u], 1);
    }
    __syncthreads();
    scan[t] = hist[t];
    __syncthreads();
    for (int s = 1; s < 256; s <<= 1) {
        int u = (t >= s) ? scan[t - s] : 0;
        __syncthreads();
        scan[t] += u;
        __syncthreads();
    }
    int excl = scan[t] - hist[t];
    cur[t] = excl + valid;
    if (valid) eb[excl] = (((unsigned)node) << 8) | ((unsigned)node & 255u);   // self-loop first
    __syncthreads();
    {
        int i = t;
        for (; i + 768 < cnt; i += 1024) {
            unsigned v0 = pb[i], v1 = pb[i + 256], v2 = pb[i + 512], v3 = pb[i + 768];
            int p0 = atomicAdd(&cur[v0 & 255u], 1);
            int p1 = atomicAdd(&cur[v1 & 255u], 1);
            int p2 = atomicAdd(&cur[v2 & 255u], 1);
            int p3 = atomicAdd(&cur[v3 & 255u], 1);
            eb[p0] = v0; eb[p1] = v1; eb[p2] = v2; eb[p3] = v3;
        }
        for (; i < cnt; i += 256) {
            unsigned int val = pb[i];
            int pos = atomicAdd(&cur[val & 255u], 1);
            eb[pos] = val;
        }
    }
    if (valid) {
        deg3[v * NN + node] = hist[t];
        start3[v * NN + node] = obase + excl;
    }
}

// ---------------------------------------------------------------- GAT aggregate (wave/dst, fp16 xh)
// Preamble per 64-edge tile: each lane computes its edge's 4 head weights in FP32, writes them
// TRANSPOSED to LDS w[h][j] (stride 65 -> conflict-free), accumulates per-lane den partials.
// Inner loop per edge: 1 readlane(src) + 1 ds_read_b32 (16-lane broadcast, fp32 weight ready)
// + 1 global load + 2 fma. No fp16 weight round-trip at all.
__global__ __launch_bounds__(256) void aggregate_kernel(const unsigned short* __restrict__ xh,
                                                        const int* __restrict__ start,
                                                        const int* __restrict__ deg,
                                                        const unsigned int* __restrict__ ebuf,
                                                        const float* __restrict__ a_src,
                                                        const float* __restrict__ a_dst,
                                                        const float* __restrict__ bias,
                                                        const float* __restrict__ gw,
                                                        const float* __restrict__ gb,
                                                        unsigned short* __restrict__ hvb,
                                                        float* __restrict__ gexpv) {
    __shared__ float wlds[4 * 260];   // per-wave region: 260 floats = 4 heads * 65 (stride pad)
    int node = (blockIdx.x * 256 + threadIdx.x) >> 6;
    int lane = threadIdx.x & 63;
    if (node >= NN) return;
    int h = lane >> 4;
    int st = start[node];
    int cnt = deg[node];
    const char* xb = (const char*)xh;
    int laneoff = lane * 4;                 // byte offset within 256B fp16 row
    float4 ad4 = *(const float4*)(a_dst + (size_t)node * 4);
    float* ww = wlds + (threadIdx.x >> 6) * 260;     // this wave's region
    const float* wr = ww + h * 65;                   // this lane's head row

    float accx = 0.f, accy = 0.f;
    float d0s = 0.f, d1s = 0.f, d2s = 0.f, d3s = 0.f;
    for (int j0 = 0; j0 < cnt; j0 += 64) {
        int nj = min(64, cnt - j0);
        int src_l = 0;
        if (lane < nj) {
            src_l = (int)(ebuf[st + j0 + lane] >> 8);
            float4 as4 = *(const float4*)(a_src + (size_t)src_l * 4);
            float t0 = as4.x + ad4.x, t1 = as4.y + ad4.y;
            float t2 = as4.z + ad4.z, t3 = as4.w + ad4.w;
            t0 = fmaxf(t0, 0.f) + 0.2f * fminf(t0, 0.f);
            t1 = fmaxf(t1, 0.f) + 0.2f * fminf(t1, 0.f);
            t2 = fmaxf(t2, 0.f) + 0.2f * fminf(t2, 0.f);
            t3 = fmaxf(t3, 0.f) + 0.2f * fminf(t3, 0.f);
            float w0 = exp2f(t0 * LOG2E);
            float w1 = exp2f(t1 * LOG2E);
            float w2 = exp2f(t2 * LOG2E);
            float w3 = exp2f(t3 * LOG2E);
            d0s += w0; d1s += w1; d2s += w2; d3s += w3;
            ww[0 * 65 + lane] = w0;
            ww[1 * 65 + lane] = w1;
            ww[2 * 65 + lane] = w2;
            ww[3 * 65 + lane] = w3;
        }
        // same wave produces and consumes: compiler inserts lgkmcnt wait, no barrier needed
        int jj = 0;
        for (; jj + 4 <= nj; jj += 4) {
            int s0 = __builtin_amdgcn_readlane(src_l, jj);
            int s1 = __builtin_amdgcn_readlane(src_l, jj + 1);
            int s2 = __builtin_amdgcn_readlane(src_l, jj + 2);
            int s3 = __builtin_amdgcn_readlane(src_l, jj + 3);
            float w0 = wr[jj];
            float w1 = wr[jj + 1];
            float w2 = wr[jj + 2];
            float w3 = wr[jj + 3];
            __half2 x0 = *(const __half2*)(xb + (((size_t)(unsigned)s0) << 8) + laneoff);
            __half2 x1 = *(const __half2*)(xb + (((size_t)(unsigned)s1) << 8) + laneoff);
            __half2 x2 = *(const __half2*)(xb + (((size_t)(unsigned)s2) << 8) + laneoff);
            __half2 x3 = *(const __half2*)(xb + (((size_t)(unsigned)s3) << 8) + laneoff);
            accx = fmaf(__low2float(x0), w0, accx);
            accy = fmaf(__high2float(x0), w0, accy);
            accx = fmaf(__low2float(x1), w1, accx);
            accy = fmaf(__high2float(x1), w1, accy);
            accx = fmaf(__low2float(x2), w2, accx);
            accy = fmaf(__high2float(x2), w2, accy);
            accx = fmaf(__low2float(x3), w3, accx);
            accy = fmaf(__high2float(x3), w3, accy);
        }
        for (; jj < nj; jj++) {
            int s = __builtin_amdgcn_readlane(src_l, jj);
            float w = wr[jj];
            __half2 xv = *(const __half2*)(xb + (((size_t)(unsigned)s) << 8) + laneoff);
            accx = fmaf(__low2float(xv), w, accx);
            accy = fmaf(__high2float(xv), w, accy);
        }
    }
    // reduce the 4 per-head denominators across lanes; select own head
    #pragma unroll
    for (int m = 1; m < 64; m <<= 1) {
        d0s += __shfl_xor(d0s, m);
        d1s += __shfl_xor(d1s, m);
        d2s += __shfl_xor(d2s, m);
        d3s += __shfl_xor(d3s, m);
    }
    float den = (h == 0) ? d0s : (h == 1) ? d1s : (h == 2) ? d2s : d3s;
    float inv = 1.0f / den;
    float2 bb = *(const float2*)(bias + lane * 2);
    float o0 = accx * inv + bb.x;
    float o1 = accy * inv + bb.y;
    o0 = o0 > 0.f ? o0 : exp2f(o0 * LOG2E) - 1.0f;   // ELU
    o1 = o1 > 0.f ? o1 : exp2f(o1 * LOG2E) - 1.0f;
    unsigned int packed = (unsigned)f2h(o0) | ((unsigned)f2h(o1) << 16);
    *(unsigned int*)(hvb + (size_t)node * 128 + lane * 2) = packed;
    float2 g2 = *(const float2*)(gw + lane * 2);
    float gp = o0 * g2.x + o1 * g2.y;
    #pragma unroll
    for (int m = 1; m < 64; m <<= 1) gp += __shfl_xor(gp, m);
    if (lane == 0) gexpv[node] = exp2f((gp + gb[0]) * LOG2E);
}

// ---------------------------------------------------------------- pool: block/graph (fp16 hv)
__global__ __launch_bounds__(1024) void pool_kernel(const unsigned short* __restrict__ hvb,
                                                    const float* __restrict__ gexpv,
                                                    const int* __restrict__ batch,
                                                    float* __restrict__ gout,
                                                    int voff) {
    int b = blockIdx.x;
    int g = threadIdx.x >> 7;
    int ch = threadIdx.x & 127;
    int l = 0, r = NN;
    while (l < r) { int m = (l + r) >> 1; if (batch[m] < b) l = m + 1; else r = m; }
    int s0 = l;
    r = NN;
    while (l < r) { int m = (l + r) >> 1; if (batch[m] < b + 1) l = m + 1; else r = m; }
    int s1 = l;
    float acc = 0.f, wsum = 0.f;
    for (int n = s0 + g; n < s1; n += 8) {
        float w = gexpv[n];
        wsum += w;
        acc = fmaf(w, h2f(hvb[(size_t)n * 128 + ch]), acc);
    }
    __shared__ float sacc[8][128];
    __shared__ float sws[8];
    sacc[g][ch] = acc;
    if (ch == 0) sws[g] = wsum;
    __syncthreads();
    if (g == 0) {
        float a = 0.f, w = 0.f;
        #pragma unroll
        for (int i = 0; i < 8; i++) { a += sacc[i][ch]; w += sws[i]; }
        gout[b * 384 + voff + ch] = (s1 > s0) ? a / w : 0.f;
    }
}

// ---------------------------------------------------------------- classifier
__global__ __launch_bounds__(128) void clf_kernel(const float* __restrict__ gout,
                                                  const float* __restrict__ W1,
                                                  const float* __restrict__ b1,
                                                  const float* __restrict__ W2,
                                                  const float* __restrict__ b2,
                                                  float* __restrict__ out) {
    int b = blockIdx.x;
    int j = threadIdx.x;
    float acc = b1[j];
    for (int k = 0; k < 384; k++) acc = fmaf(gout[b * 384 + k], W1[k * 128 + j], acc);
    acc = acc > 0.f ? acc : 0.01f * acc;
    float p = acc * W2[j];
    #pragma unroll
    for (int m = 1; m < 64; m <<= 1) p += __shfl_xor(p, m);
    __shared__ float sh[2];
    if ((j & 63) == 0) sh[j >> 6] = p;
    __syncthreads();
    if (j == 0) out[b] = sh[0] + sh[1] + b2[0];
}

// ---------------------------------------------------------------- launch
extern "C" void kernel_launch(void* const* d_in, const int* in_sizes, int n_in,
                              void* d_out, int out_size, void* d_ws, size_t ws_size,
                              hipStream_t stream) {
    const float* x      = (const float*)d_in[0];
    const int*   ei[3]  = {(const int*)d_in[1], (const int*)d_in[2], (const int*)d_in[3]};
    const int*   batch  = (const int*)d_in[4];
    const float* ln_g   = (const float*)d_in[5];
    const float* ln_b   = (const float*)d_in[6];
    const float* proj_W = (const float*)d_in[7];
    const float* proj_b = (const float*)d_in[8];
    const float* Wv[3]  = {(const float*)d_in[9],  (const float*)d_in[13], (const float*)d_in[17]};
    const float* asv[3] = {(const float*)d_in[10], (const float*)d_in[14], (const float*)d_in[18]};
    const float* adv[3] = {(const float*)d_in[11], (const float*)d_in[15], (const float*)d_in[19]};
    const float* bv[3]  = {(const float*)d_in[12], (const float*)d_in[16], (const float*)d_in[20]};
    const float* gate_W = (const float*)d_in[21];
    const float* gate_b = (const float*)d_in[22];
    const float* clf_W1 = (const float*)d_in[23];
    const float* clf_b1 = (const float*)d_in[24];
    const float* clf_W2 = (const float*)d_in[25];
    const float* clf_b2 = (const float*)d_in[26];
    float* out = (float*)d_out;

    (void)in_sizes; (void)n_in; (void)out_size; (void)ws_size;

    // ---- workspace layout ----
    char* base = (char*)d_ws;
    size_t off = 0;
    auto nxt = [&](size_t bytes) { char* r = base + off; off += (bytes + 255) & ~(size_t)255; return r; };
    unsigned short* h0   = (unsigned short*)nxt((size_t)ROWS_PAD * 128 * 2);   // bf16
    unsigned short* xh   = (unsigned short*)nxt((size_t)ROWS_PAD * 128 * 2);   // fp16
    unsigned short* hvb  = (unsigned short*)nxt((size_t)NN * 128 * 2);         // fp16
    unsigned short* WT   = (unsigned short*)nxt(4 * 16384 * 2);
    float* c12    = (float*)nxt(256 * 4);
    float* a_src  = (float*)nxt((size_t)ROWS_PAD * 4 * 4);
    float* a_dst  = (float*)nxt((size_t)ROWS_PAD * 4 * 4);
    float* gexpv  = (float*)nxt(NN * 4);
    float* gout   = (float*)nxt(BB * 384 * 4);
    int* deg3     = (int*)nxt(3 * NN * 4);
    int* start3   = (int*)nxt(3 * NN * 4);
    unsigned int* ebuf3 = (unsigned int*)nxt(((size_t)3 * EPV + 64) * 4);
    int* btot     = (int*)nxt(3 * NBUCK * 4);
    int* ebstart  = (int*)nxt(3 * (NBUCK + 1) * 4);
    int* bstart   = (int*)nxt(3 * (NBUCK + 1) * 4);
    int* blockHistT = (int*)nxt((size_t)NBUCK * TOTB * 4);
    int* blockOffT  = (int*)nxt((size_t)NBUCK * TOTB * 4);
    unsigned int* pairbuf = (unsigned int*)nxt((size_t)3 * EE * 4);

    // 1-2. weight packs + LN affine constants
    pack_wt<<<dim3(64, 4), 256, 0, stream>>>(proj_W, Wv[0], Wv[1], Wv[2], ln_g, WT);
    ln_consts<<<1, 128, 0, stream>>>(proj_W, ln_g, ln_b, c12);
    // 3. CSR histogram || proj GEMM (fused LN)
    fat_hist_proj<<<TOTB + 782, 256, 0, stream>>>(ei[0], ei[1], ei[2], blockHistT,
                                                  x, WT, c12, proj_b, h0);
    // 4-6. bucket totals, starts, per-block offsets
    csr_bsum<<<(3 * NBUCK + 3) / 4, 256, 0, stream>>>(blockHistT, btot);
    csr_scan<<<3, 512, 0, stream>>>(btot, ebstart, bstart);
    csr_boff<<<(3 * NBUCK + 3) / 4, 256, 0, stream>>>(blockHistT, ebstart, blockOffT);
    // 7. coarse scatter || view-0 GEMM
    fat_scatter_view<<<TOTB + 782, 256, 0, stream>>>(ei[0], ei[1], ei[2], blockOffT, pairbuf,
                                                     h0, WT, asv[0], adv[0], xh, a_src, a_dst);
    // 8. fine sort (+self-loops)
    csr_fine<<<3 * NBUCK, 256, 0, stream>>>(pairbuf, btot, ebstart, bstart, deg3, start3, ebuf3);
    // 9+. per view: (GEMM for v>0), aggregate, pool
    for (int v = 0; v < 3; v++) {
        if (v > 0)
            gemm_view<<<782, 256, 0, stream>>>(h0, WT + (size_t)(1 + v) * 16384,
                                               asv[v], adv[v], xh, a_src, a_dst);
        aggregate_kernel<<<25000, 256, 0, stream>>>(xh, start3 + v * NN, deg3 + v * NN,
                                                    ebuf3 + (size_t)v * EPV,
                                                    a_src, a_dst,
                                                    bv[v], gate_W, gate_b, hvb, gexpv);
        pool_kernel<<<256, 1024, 0, stream>>>(hvb, gexpv, batch, gout, v * 128);
    }
    // classifier
    clf_kernel<<<256, 128, 0, stream>>>(gout, clf_W1, clf_b1, clf_W2, clf_b2, out);
}

// Round 2
// 629.085 us; speedup vs baseline: 1.0924x; 1.0924x over previous
//
#include <hip/hip_runtime.h>
#include <hip/hip_bf16.h>
#include <hip/hip_fp16.h>
#include <math.h>

#define NN 100000
#define EE 1600000
#define BB 256
#define NBUCK 391          // ceil(NN/256) coarse buckets (dst>>8)
#define PBLK 384           // blocks per view in bucket pass
#define CH 4167            // edges per block (384*4167 >= EE)
#define TOTB (3 * PBLK)    // total bucket-pass blocks
#define ROWS_PAD 100096    // 782*128
#define EPV (EE + NN)      // entries per view incl self-loops
#define LOG2E 1.442695041f
#define GEMM_BLKS 782
#define AGG_BLKS 25000
#define XH_ELEMS ((size_t)ROWS_PAD * 128)
#define A_ELEMS ((size_t)ROWS_PAD * 4)
#define HV_ELEMS ((size_t)NN * 128)

typedef short bf16x8 __attribute__((ext_vector_type(8)));
typedef float f32x4 __attribute__((ext_vector_type(4)));

__device__ __forceinline__ unsigned short f2bf(float f) {
    __hip_bfloat16 h = __float2bfloat16(f);   // RNE
    return *(unsigned short*)&h;
}
__device__ __forceinline__ unsigned short f2h(float f) {
    __half h = __float2half(f);               // RNE
    return *(unsigned short*)&h;
}
__device__ __forceinline__ float h2f(unsigned short u) {
    __half h = *(__half*)&u;
    return __half2float(h);
}

// ---------------------------------------------------------------- pack W^T to bf16 [n][k]
// which==0 (proj): fold ln_g -> bf16(g[k]*W[k,n])
__global__ __launch_bounds__(256) void pack_wt(const float* __restrict__ W0,
                                               const float* __restrict__ W1,
                                               const float* __restrict__ W2,
                                               const float* __restrict__ W3,
                                               const float* __restrict__ ln_g,
                                               unsigned short* __restrict__ WT) {
    int which = blockIdx.y;
    const float* W = which == 0 ? W0 : which == 1 ? W1 : which == 2 ? W2 : W3;
    int i = blockIdx.x * 256 + threadIdx.x;   // 0..16383
    int n = i >> 7, k = i & 127;
    float v = W[k * 128 + n];
    if (which == 0) v *= ln_g[k];
    WT[which * 16384 + i] = f2bf(v);
}

// ---------------------------------------------------------------- LN affine constants (k-split)
__global__ __launch_bounds__(512) void ln_consts(const float* __restrict__ W,
                                                 const float* __restrict__ g,
                                                 const float* __restrict__ b,
                                                 float* __restrict__ c12) {
    __shared__ float p1[512], p2[512];
    int t = threadIdx.x;
    int n = t & 127, kg = t >> 7;            // 4 k-groups of 32
    float c1 = 0.f, c2 = 0.f;
    for (int k = kg * 32; k < kg * 32 + 32; k++) {
        float w = W[k * 128 + n];
        c1 = fmaf(g[k], w, c1);
        c2 = fmaf(b[k], w, c2);
    }
    p1[t] = c1; p2[t] = c2;
    __syncthreads();
    if (kg == 0) {
        c1 = p1[n] + p1[128 + n] + p1[256 + n] + p1[384 + n];
        c2 = p2[n] + p2[128 + n] + p2[256 + n] + p2[384 + n];
        c12[n] = c1;
        c12[128 + n] = c2;
    }
}

// ================================================================ device bodies

// ---- coarse histogram body (blockHistT layout [bucket][TOTB])
__device__ __forceinline__ void hist_body(int bid, int tid,
                                          const int* __restrict__ e0,
                                          const int* __restrict__ e1,
                                          const int* __restrict__ e2,
                                          int* __restrict__ blockHistT) {
    int v = bid / PBLK, p = bid % PBLK;
    const int* ei = v == 0 ? e0 : v == 1 ? e1 : e2;
    __shared__ int h[NBUCK];
    for (int i = tid; i < NBUCK; i += 256) h[i] = 0;
    __syncthreads();
    int ea = p * CH, ebnd = min(EE, ea + CH);
    int e = ea + tid;
    for (; e + 768 < ebnd; e += 1024) {
        int d0 = ei[EE + e], d1 = ei[EE + e + 256];
        int d2 = ei[EE + e + 512], d3 = ei[EE + e + 768];
        atomicAdd(&h[((unsigned)d0) >> 8], 1);
        atomicAdd(&h[((unsigned)d1) >> 8], 1);
        atomicAdd(&h[((unsigned)d2) >> 8], 1);
        atomicAdd(&h[((unsigned)d3) >> 8], 1);
    }
    for (; e < ebnd; e += 256) atomicAdd(&h[((unsigned)ei[EE + e]) >> 8], 1);
    __syncthreads();
    for (int i = tid; i < NBUCK; i += 256) blockHistT[i * TOTB + bid] = h[i];
}

// ---- proj GEMM body (fused LayerNorm), writes h0 bf16
__device__ __forceinline__ void proj_body(int nb, int tid,
                                          const float* __restrict__ X,
                                          const unsigned short* __restrict__ WT,
                                          const float* __restrict__ c12,
                                          const float* __restrict__ pb,
                                          unsigned short* __restrict__ Out) {
    int w = tid >> 6, lane = tid & 63;
    int ln = lane & 15, oct = lane >> 4;
    int row0 = nb * 128 + w * 32;

    f32x4 acc[2][8];
    #pragma unroll
    for (int i = 0; i < 2; i++)
        #pragma unroll
        for (int j = 0; j < 8; j++) acc[i][j] = (f32x4){0.f, 0.f, 0.f, 0.f};

    const float* X0 = X + (size_t)min(row0 + ln, NN - 1) * 128;
    const float* X1 = X + (size_t)min(row0 + 16 + ln, NN - 1) * 128;
    const bf16x8* Wr = (const bf16x8*)(WT + (size_t)ln * 128);

    float s0 = 0.f, q0 = 0.f, s1 = 0.f, q1 = 0.f;
    #pragma unroll
    for (int kq = 0; kq < 4; kq++) {
        int koff = kq * 4 + oct;
        float4 xa = *(const float4*)(X0 + koff * 8);
        float4 xb = *(const float4*)(X0 + koff * 8 + 4);
        float4 ya = *(const float4*)(X1 + koff * 8);
        float4 yb = *(const float4*)(X1 + koff * 8 + 4);
        s0 += (xa.x + xa.y) + (xa.z + xa.w) + (xb.x + xb.y) + (xb.z + xb.w);
        q0 += xa.x * xa.x + xa.y * xa.y + xa.z * xa.z + xa.w * xa.w
            + xb.x * xb.x + xb.y * xb.y + xb.z * xb.z + xb.w * xb.w;
        s1 += (ya.x + ya.y) + (ya.z + ya.w) + (yb.x + yb.y) + (yb.z + yb.w);
        q1 += ya.x * ya.x + ya.y * ya.y + ya.z * ya.z + ya.w * ya.w
            + yb.x * yb.x + yb.y * yb.y + yb.z * yb.z + yb.w * yb.w;
        bf16x8 a0, a1;
        a0[0] = (short)f2bf(xa.x); a0[1] = (short)f2bf(xa.y); a0[2] = (short)f2bf(xa.z); a0[3] = (short)f2bf(xa.w);
        a0[4] = (short)f2bf(xb.x); a0[5] = (short)f2bf(xb.y); a0[6] = (short)f2bf(xb.z); a0[7] = (short)f2bf(xb.w);
        a1[0] = (short)f2bf(ya.x); a1[1] = (short)f2bf(ya.y); a1[2] = (short)f2bf(ya.z); a1[3] = (short)f2bf(ya.w);
        a1[4] = (short)f2bf(yb.x); a1[5] = (short)f2bf(yb.y); a1[6] = (short)f2bf(yb.z); a1[7] = (short)f2bf(yb.w);
        #pragma unroll
        for (int ct = 0; ct < 8; ct++) {
            bf16x8 bfr = Wr[ct * 16 * 16 + koff];
            acc[0][ct] = __builtin_amdgcn_mfma_f32_16x16x32_bf16(a0, bfr, acc[0][ct], 0, 0, 0);
            acc[1][ct] = __builtin_amdgcn_mfma_f32_16x16x32_bf16(a1, bfr, acc[1][ct], 0, 0, 0);
        }
    }
    #pragma unroll
    for (int m = 16; m < 64; m <<= 1) {
        s0 += __shfl_xor(s0, m); q0 += __shfl_xor(q0, m);
        s1 += __shfl_xor(s1, m); q1 += __shfl_xor(q1, m);
    }
    float mu0 = s0 * (1.0f / 128.0f);
    float rs0 = rsqrtf(q0 * (1.0f / 128.0f) - mu0 * mu0 + 1e-5f);
    float mu1 = s1 * (1.0f / 128.0f);
    float rs1 = rsqrtf(q1 * (1.0f / 128.0f) - mu1 * mu1 + 1e-5f);

    float c1v[8], c2v[8], pbv[8];
    #pragma unroll
    for (int ct = 0; ct < 8; ct++) {
        c1v[ct] = c12[ct * 16 + ln];
        c2v[ct] = c12[128 + ct * 16 + ln];
        pbv[ct] = pb[ct * 16 + ln];
    }
    #pragma unroll
    for (int rt = 0; rt < 2; rt++) {
        #pragma unroll
        for (int r = 0; r < 4; r++) {
            int src = oct * 4 + r;
            float rs_r = __shfl(rt ? rs1 : rs0, src);
            float mu_r = __shfl(rt ? mu1 : mu0, src);
            int row = row0 + rt * 16 + oct * 4 + r;
            #pragma unroll
            for (int ct = 0; ct < 8; ct++) {
                float v = rs_r * acc[rt][ct][r] - rs_r * mu_r * c1v[ct] + c2v[ct] + pbv[ct];
                v = v > 0.f ? v : 0.01f * v;
                Out[(size_t)row * 128 + ct * 16 + ln] = f2bf(v);
            }
        }
    }
}

// ---- coarse scatter body
__device__ __forceinline__ void scatter_body(int bid, int tid,
                                             const int* __restrict__ e0,
                                             const int* __restrict__ e1,
                                             const int* __restrict__ e2,
                                             const int* __restrict__ blockOffT,
                                             unsigned int* __restrict__ pairbuf) {
    int v = bid / PBLK, p = bid % PBLK;
    const int* ei = v == 0 ? e0 : v == 1 ? e1 : e2;
    __shared__ int cur[NBUCK];
    for (int i = tid; i < NBUCK; i += 256) cur[i] = blockOffT[(size_t)i * TOTB + bid];
    __syncthreads();
    int ea = p * CH, ebnd = min(EE, ea + CH);
    unsigned int* pbuf = pairbuf + (size_t)v * EE;
    int e = ea + tid;
    for (; e + 768 < ebnd; e += 1024) {
        unsigned s0 = (unsigned)ei[e],       d0 = (unsigned)ei[EE + e];
        unsigned s1 = (unsigned)ei[e + 256], d1 = (unsigned)ei[EE + e + 256];
        unsigned s2 = (unsigned)ei[e + 512], d2 = (unsigned)ei[EE + e + 512];
        unsigned s3 = (unsigned)ei[e + 768], d3 = (unsigned)ei[EE + e + 768];
        int p0 = atomicAdd(&cur[d0 >> 8], 1);
        int p1 = atomicAdd(&cur[d1 >> 8], 1);
        int p2 = atomicAdd(&cur[d2 >> 8], 1);
        int p3 = atomicAdd(&cur[d3 >> 8], 1);
        pbuf[p0] = (s0 << 8) | (d0 & 255u);
        pbuf[p1] = (s1 << 8) | (d1 & 255u);
        pbuf[p2] = (s2 << 8) | (d2 & 255u);
        pbuf[p3] = (s3 << 8) | (d3 & 255u);
    }
    for (; e < ebnd; e += 256) {
        unsigned s = (unsigned)ei[e], d = (unsigned)ei[EE + e];
        int pos = atomicAdd(&cur[d >> 8], 1);
        pbuf[pos] = (s << 8) | (d & 255u);
    }
}

// ---- view GEMM body (bf16 A in, fp16 xh out, fused att reduction)
__device__ __forceinline__ void view_body(int nb, int tid,
                                          const unsigned short* __restrict__ h0,
                                          const unsigned short* __restrict__ WTv,
                                          const float* __restrict__ asw,
                                          const float* __restrict__ adw,
                                          unsigned short* __restrict__ Out,
                                          float* __restrict__ a_src,
                                          float* __restrict__ a_dst) {
    int w = tid >> 6, lane = tid & 63;
    int ln = lane & 15, oct = lane >> 4;
    int row0 = nb * 128 + w * 32;

    f32x4 acc[2][8];
    #pragma unroll
    for (int i = 0; i < 2; i++)
        #pragma unroll
        for (int j = 0; j < 8; j++) acc[i][j] = (f32x4){0.f, 0.f, 0.f, 0.f};

    const bf16x8* Ar0 = (const bf16x8*)(h0 + (size_t)(row0 + ln) * 128);
    const bf16x8* Ar1 = (const bf16x8*)(h0 + (size_t)(row0 + 16 + ln) * 128);
    const bf16x8* Wr  = (const bf16x8*)(WTv + (size_t)ln * 128);

    #pragma unroll
    for (int kq = 0; kq < 4; kq++) {
        int koff = kq * 4 + oct;
        bf16x8 a0 = Ar0[koff];
        bf16x8 a1 = Ar1[koff];
        #pragma unroll
        for (int ct = 0; ct < 8; ct++) {
            bf16x8 bfr = Wr[ct * 16 * 16 + koff];
            acc[0][ct] = __builtin_amdgcn_mfma_f32_16x16x32_bf16(a0, bfr, acc[0][ct], 0, 0, 0);
            acc[1][ct] = __builtin_amdgcn_mfma_f32_16x16x32_bf16(a1, bfr, acc[1][ct], 0, 0, 0);
        }
    }
    float aswv[8], adwv[8];
    #pragma unroll
    for (int ct = 0; ct < 8; ct++) { aswv[ct] = asw[ct * 16 + ln]; adwv[ct] = adw[ct * 16 + ln]; }

    #pragma unroll
    for (int rt = 0; rt < 2; rt++) {
        #pragma unroll
        for (int r = 0; r < 4; r++) {
            int row = row0 + rt * 16 + oct * 4 + r;
            float sh_[4] = {0.f, 0.f, 0.f, 0.f}, dh_[4] = {0.f, 0.f, 0.f, 0.f};
            #pragma unroll
            for (int ct = 0; ct < 8; ct++) {
                float vv = acc[rt][ct][r];
                Out[(size_t)row * 128 + ct * 16 + ln] = f2h(vv);
                sh_[ct >> 1] = fmaf(vv, aswv[ct], sh_[ct >> 1]);
                dh_[ct >> 1] = fmaf(vv, adwv[ct], dh_[ct >> 1]);
            }
            #pragma unroll
            for (int off = 1; off < 16; off <<= 1) {
                #pragma unroll
                for (int h = 0; h < 4; h++) {
                    sh_[h] += __shfl_xor(sh_[h], off);
                    dh_[h] += __shfl_xor(dh_[h], off);
                }
            }
            if (ln == 0) {
                *(float4*)(a_src + (size_t)row * 4) = make_float4(sh_[0], sh_[1], sh_[2], sh_[3]);
                *(float4*)(a_dst + (size_t)row * 4) = make_float4(dh_[0], dh_[1], dh_[2], dh_[3]);
            }
        }
    }
}

// ---- GAT aggregate body (wave/dst, fp16 xh)
__device__ __forceinline__ void agg_body(int node, int tid,
                                         const unsigned short* __restrict__ xh,
                                         const int* __restrict__ start,
                                         const int* __restrict__ deg,
                                         const unsigned int* __restrict__ ebuf,
                                         const float* __restrict__ a_src,
                                         const float* __restrict__ a_dst,
                                         const float* __restrict__ bias,
                                         const float* __restrict__ gw,
                                         const float* __restrict__ gb,
                                         unsigned short* __restrict__ hvb,
                                         float* __restrict__ gexpv,
                                         float* wlds) {
    int lane = tid & 63;
    int h = lane >> 4;
    int st = start[node];
    int cnt = deg[node];
    const char* xb = (const char*)xh;
    int laneoff = lane * 4;                 // byte offset within 256B fp16 row
    float4 ad4 = *(const float4*)(a_dst + (size_t)node * 4);
    float* ww = wlds + (tid >> 6) * 260;    // this wave's region
    const float* wr = ww + h * 65;          // this lane's head row

    float accx = 0.f, accy = 0.f;
    float d0s = 0.f, d1s = 0.f, d2s = 0.f, d3s = 0.f;
    for (int j0 = 0; j0 < cnt; j0 += 64) {
        int nj = min(64, cnt - j0);
        int src_l = 0;
        if (lane < nj) {
            src_l = (int)(ebuf[st + j0 + lane] >> 8);
            float4 as4 = *(const float4*)(a_src + (size_t)src_l * 4);
            float t0 = as4.x + ad4.x, t1 = as4.y + ad4.y;
            float t2 = as4.z + ad4.z, t3 = as4.w + ad4.w;
            t0 = fmaxf(t0, 0.f) + 0.2f * fminf(t0, 0.f);
            t1 = fmaxf(t1, 0.f) + 0.2f * fminf(t1, 0.f);
            t2 = fmaxf(t2, 0.f) + 0.2f * fminf(t2, 0.f);
            t3 = fmaxf(t3, 0.f) + 0.2f * fminf(t3, 0.f);
            float w0 = exp2f(t0 * LOG2E);
            float w1 = exp2f(t1 * LOG2E);
            float w2 = exp2f(t2 * LOG2E);
            float w3 = exp2f(t3 * LOG2E);
            d0s += w0; d1s += w1; d2s += w2; d3s += w3;
            ww[0 * 65 + lane] = w0;
            ww[1 * 65 + lane] = w1;
            ww[2 * 65 + lane] = w2;
            ww[3 * 65 + lane] = w3;
        }
        // same wave produces and consumes: compiler inserts lgkmcnt wait, no barrier needed
        int jj = 0;
        for (; jj + 4 <= nj; jj += 4) {
            int s0 = __builtin_amdgcn_readlane(src_l, jj);
            int s1 = __builtin_amdgcn_readlane(src_l, jj + 1);
            int s2 = __builtin_amdgcn_readlane(src_l, jj + 2);
            int s3 = __builtin_amdgcn_readlane(src_l, jj + 3);
            float w0 = wr[jj];
            float w1 = wr[jj + 1];
            float w2 = wr[jj + 2];
            float w3 = wr[jj + 3];
            __half2 x0 = *(const __half2*)(xb + (((size_t)(unsigned)s0) << 8) + laneoff);
            __half2 x1 = *(const __half2*)(xb + (((size_t)(unsigned)s1) << 8) + laneoff);
            __half2 x2 = *(const __half2*)(xb + (((size_t)(unsigned)s2) << 8) + laneoff);
            __half2 x3 = *(const __half2*)(xb + (((size_t)(unsigned)s3) << 8) + laneoff);
            accx = fmaf(__low2float(x0), w0, accx);
            accy = fmaf(__high2float(x0), w0, accy);
            accx = fmaf(__low2float(x1), w1, accx);
            accy = fmaf(__high2float(x1), w1, accy);
            accx = fmaf(__low2float(x2), w2, accx);
            accy = fmaf(__high2float(x2), w2, accy);
            accx = fmaf(__low2float(x3), w3, accx);
            accy = fmaf(__high2float(x3), w3, accy);
        }
        for (; jj < nj; jj++) {
            int s = __builtin_amdgcn_readlane(src_l, jj);
            float w = wr[jj];
            __half2 xv = *(const __half2*)(xb + (((size_t)(unsigned)s) << 8) + laneoff);
            accx = fmaf(__low2float(xv), w, accx);
            accy = fmaf(__high2float(xv), w, accy);
        }
    }
    // reduce the 4 per-head denominators across lanes; select own head
    #pragma unroll
    for (int m = 1; m < 64; m <<= 1) {
        d0s += __shfl_xor(d0s, m);
        d1s += __shfl_xor(d1s, m);
        d2s += __shfl_xor(d2s, m);
        d3s += __shfl_xor(d3s, m);
    }
    float den = (h == 0) ? d0s : (h == 1) ? d1s : (h == 2) ? d2s : d3s;
    float inv = 1.0f / den;
    float2 bb = *(const float2*)(bias + lane * 2);
    float o0 = accx * inv + bb.x;
    float o1 = accy * inv + bb.y;
    o0 = o0 > 0.f ? o0 : exp2f(o0 * LOG2E) - 1.0f;   // ELU
    o1 = o1 > 0.f ? o1 : exp2f(o1 * LOG2E) - 1.0f;
    unsigned int packed = (unsigned)f2h(o0) | ((unsigned)f2h(o1) << 16);
    *(unsigned int*)(hvb + (size_t)node * 128 + lane * 2) = packed;
    float2 g2 = *(const float2*)(gw + lane * 2);
    float gp = o0 * g2.x + o1 * g2.y;
    #pragma unroll
    for (int m = 1; m < 64; m <<= 1) gp += __shfl_xor(gp, m);
    if (lane == 0) gexpv[node] = exp2f((gp + gb[0]) * LOG2E);
}

// ---- pool body: one graph b, one view's hv/gexp
__device__ __forceinline__ void pool_body(int b, int tid,
                                          const unsigned short* __restrict__ hvb,
                                          const float* __restrict__ gexpv,
                                          const int* __restrict__ batch,
                                          float* __restrict__ gout,
                                          int voff,
                                          float* sacc, float* sws) {
    int g = tid >> 7;
    int ch = tid & 127;
    int l = 0, r = NN;
    while (l < r) { int m = (l + r) >> 1; if (batch[m] < b) l = m + 1; else r = m; }
    int s0 = l;
    r = NN;
    while (l < r) { int m = (l + r) >> 1; if (batch[m] < b + 1) l = m + 1; else r = m; }
    int s1 = l;
    float acc = 0.f, wsum = 0.f;
    for (int n = s0 + g; n < s1; n += 8) {
        float w = gexpv[n];
        wsum += w;
        acc = fmaf(w, h2f(hvb[(size_t)n * 128 + ch]), acc);
    }
    sacc[g * 128 + ch] = acc;
    if (ch == 0) sws[g] = wsum;
    __syncthreads();
    if (g == 0) {
        float a = 0.f, w = 0.f;
        #pragma unroll
        for (int i = 0; i < 8; i++) { a += sacc[i * 128 + ch]; w += sws[i]; }
        gout[b * 384 + voff + ch] = (s1 > s0) ? a / w : 0.f;
    }
}

// ================================================================ fat/merged kernels
__global__ __launch_bounds__(256) void fat_hist_proj(const int* e0, const int* e1, const int* e2,
                                                     int* blockHistT,
                                                     const float* X, const unsigned short* WT,
                                                     const float* c12, const float* pb,
                                                     unsigned short* h0) {
    if (blockIdx.x < TOTB) hist_body(blockIdx.x, threadIdx.x, e0, e1, e2, blockHistT);
    else proj_body(blockIdx.x - TOTB, threadIdx.x, X, WT, c12, pb, h0);
}

// fallback: scatter || view-0 GEMM
__global__ __launch_bounds__(256) void fat_scatter_view(const int* e0, const int* e1, const int* e2,
                                                        const int* blockOffT, unsigned int* pairbuf,
                                                        const unsigned short* h0, const unsigned short* WT,
                                                        const float* as0, const float* ad0,
                                                        unsigned short* xh, float* a_src, float* a_dst) {
    if (blockIdx.x < TOTB) scatter_body(blockIdx.x, threadIdx.x, e0, e1, e2, blockOffT, pairbuf);
    else view_body(blockIdx.x - TOTB, threadIdx.x, h0, WT + 16384, as0, ad0, xh, a_src, a_dst);
}

// fast: scatter || view GEMM x3 (per-view buffers)
__global__ __launch_bounds__(256) void fat_scatter_view3(const int* e0, const int* e1, const int* e2,
                                                         const int* blockOffT, unsigned int* pairbuf,
                                                         const unsigned short* h0, const unsigned short* WT,
                                                         const float* as0, const float* ad0,
                                                         const float* as1, const float* ad1,
                                                         const float* as2, const float* ad2,
                                                         unsigned short* xh3, float* a_src3, float* a_dst3) {
    if (blockIdx.x < TOTB) {
        scatter_body(blockIdx.x, threadIdx.x, e0, e1, e2, blockOffT, pairbuf);
        return;
    }
    int t = blockIdx.x - TOTB;
    int v = t / GEMM_BLKS;
    int nb = t - v * GEMM_BLKS;
    const float* as_ = v == 0 ? as0 : v == 1 ? as1 : as2;
    const float* ad_ = v == 0 ? ad0 : v == 1 ? ad1 : ad2;
    view_body(nb, threadIdx.x, h0, WT + (size_t)(1 + v) * 16384, as_, ad_,
              xh3 + (size_t)v * XH_ELEMS,
              a_src3 + (size_t)v * A_ELEMS, a_dst3 + (size_t)v * A_ELEMS);
}

__global__ __launch_bounds__(256) void gemm_view(const unsigned short* __restrict__ h0,
                                                 const unsigned short* __restrict__ WTv,
                                                 const float* __restrict__ asw,
                                                 const float* __restrict__ adw,
                                                 unsigned short* __restrict__ Out,
                                                 float* __restrict__ a_src,
                                                 float* __restrict__ a_dst) {
    view_body(blockIdx.x, threadIdx.x, h0, WTv, asw, adw, Out, a_src, a_dst);
}

// ================================================================ CSR small kernels
__global__ __launch_bounds__(256) void csr_bsum(const int* __restrict__ blockHistT,
                                                int* __restrict__ btot) {
    int wid = (blockIdx.x * 256 + threadIdx.x) >> 6;
    int lane = threadIdx.x & 63;
    if (wid >= 3 * NBUCK) return;
    int v = wid / NBUCK, b = wid - v * NBUCK;
    const int* row = blockHistT + (size_t)b * TOTB + v * PBLK;
    int s = 0;
    #pragma unroll
    for (int j = 0; j < 6; j++) s += row[lane * 6 + j];
    #pragma unroll
    for (int m = 1; m < 64; m <<= 1) s += __shfl_xor(s, m);
    if (lane == 0) btot[wid] = s;
}

__global__ __launch_bounds__(512) void csr_scan(const int* __restrict__ btot,
                                                int* __restrict__ ebstart,
                                                int* __restrict__ bstart) {
    int v = blockIdx.x, t = threadIdx.x;
    __shared__ int se[512], ss[512];
    int tot_e = (t < NBUCK) ? btot[v * NBUCK + t] : 0;
    int nval = (t < NBUCK) ? min(256, NN - t * 256) : 0;
    int tot_s = tot_e + nval;
    se[t] = tot_e; ss[t] = tot_s;
    __syncthreads();
    for (int s = 1; s < 512; s <<= 1) {
        int ae = (t >= s) ? se[t - s] : 0;
        int as_ = (t >= s) ? ss[t - s] : 0;
        __syncthreads();
        se[t] += ae; ss[t] += as_;
        __syncthreads();
    }
    if (t < NBUCK) {
        ebstart[v * (NBUCK + 1) + t] = se[t] - tot_e;
        bstart[v * (NBUCK + 1) + t] = ss[t] - tot_s;
    }
    if (t == NBUCK - 1) {
        ebstart[v * (NBUCK + 1) + NBUCK] = se[t];
        bstart[v * (NBUCK + 1) + NBUCK] = ss[t];
    }
}

__global__ __launch_bounds__(256) void csr_boff(const int* __restrict__ blockHistT,
                                                const int* __restrict__ ebstart,
                                                int* __restrict__ blockOffT) {
    int wid = (blockIdx.x * 256 + threadIdx.x) >> 6;
    int lane = threadIdx.x & 63;
    if (wid >= 3 * NBUCK) return;
    int v = wid / NBUCK, b = wid - v * NBUCK;
    const int* row = blockHistT + (size_t)b * TOTB + v * PBLK;
    int* orow = blockOffT + (size_t)b * TOTB + v * PBLK;
    int vals[6], lexcl[6];
    int ls = 0;
    #pragma unroll
    for (int j = 0; j < 6; j++) vals[j] = row[lane * 6 + j];
    #pragma unroll
    for (int j = 0; j < 6; j++) { lexcl[j] = ls; ls += vals[j]; }
    int incl = ls;
    #pragma unroll
    for (int m = 1; m < 64; m <<= 1) {
        int t = __shfl_up(incl, m);
        if (lane >= m) incl += t;
    }
    int wexcl = incl - ls;
    int base = ebstart[v * (NBUCK + 1) + b];
    #pragma unroll
    for (int j = 0; j < 6; j++) orow[lane * 6 + j] = base + wexcl + lexcl[j];
}

__global__ __launch_bounds__(256) void csr_fine(const unsigned int* __restrict__ pairbuf,
                                                const int* __restrict__ btot,
                                                const int* __restrict__ ebstart,
                                                const int* __restrict__ bstart,
                                                int* __restrict__ deg3,
                                                int* __restrict__ start3,
                                                unsigned int* __restrict__ ebuf3) {
    int v = blockIdx.x / NBUCK, b = blockIdx.x - v * NBUCK;
    int cnt   = btot[v * NBUCK + b];
    int pbase = ebstart[v * (NBUCK + 1) + b];
    int obase = bstart[v * (NBUCK + 1) + b];
    const unsigned int* pb = pairbuf + (size_t)v * EE + pbase;
    unsigned int* eb = ebuf3 + (size_t)v * EPV + obase;
    __shared__ int hist[256], scan[256], cur[256];
    int t = threadIdx.x;
    int node = b * 256 + t;
    int valid = (node < NN) ? 1 : 0;
    hist[t] = valid;
    __syncthreads();
    {
        int i = t;
        for (; i + 768 < cnt; i += 1024) {
            unsigned v0 = pb[i], v1 = pb[i + 256], v2 = pb[i + 512], v3 = pb[i + 768];
            atomicAdd(&hist[v0 & 255u], 1);
            atomicAdd(&hist[v1 & 255u], 1);
            atomicAdd(&hist[v2 & 255u], 1);
            atomicAdd(&hist[v3 & 255u], 1);
        }
        for (; i < cnt; i += 256) atomicAdd(&hist[pb[i] & 255u], 1);
    }
    __syncthreads();
    scan[t] = hist[t];
    __syncthreads();
    for (int s = 1; s < 256; s <<= 1) {
        int u = (t >= s) ? scan[t - s] : 0;
        __syncthreads();
        scan[t] += u;
        __syncthreads();
    }
    int excl = scan[t] - hist[t];
    cur[t] = excl + valid;
    if (valid) eb[excl] = (((unsigned)node) << 8) | ((unsigned)node & 255u);   // self-loop first
    __syncthreads();
    {
        int i = t;
        for (; i + 768 < cnt; i += 1024) {
            unsigned v0 = pb[i], v1 = pb[i + 256], v2 = pb[i + 512], v3 = pb[i + 768];
            int p0 = atomicAdd(&cur[v0 & 255u], 1);
            int p1 = atomicAdd(&cur[v1 & 255u], 1);
            int p2 = atomicAdd(&cur[v2 & 255u], 1);
            int p3 = atomicAdd(&cur[v3 & 255u], 1);
            eb[p0] = v0; eb[p1] = v1; eb[p2] = v2; eb[p3] = v3;
        }
        for (; i < cnt; i += 256) {
            unsigned int val = pb[i];
            int pos = atomicAdd(&cur[val & 255u], 1);
            eb[pos] = val;
        }
    }
    if (valid) {
        deg3[v * NN + node] = hist[t];
        start3[v * NN + node] = obase + excl;
    }
}

// ================================================================ aggregate kernels
__global__ __launch_bounds__(256) void aggregate_kernel(const unsigned short* __restrict__ xh,
                                                        const int* __restrict__ start,
                                                        const int* __restrict__ deg,
                                                        const unsigned int* __restrict__ ebuf,
                                                        const float* __restrict__ a_src,
                                                        const float* __restrict__ a_dst,
                                                        const float* __restrict__ bias,
                                                        const float* __restrict__ gw,
                                                        const float* __restrict__ gb,
                                                        unsigned short* __restrict__ hvb,
                                                        float* __restrict__ gexpv) {
    __shared__ float wlds[4 * 260];
    int node = (blockIdx.x * 256 + threadIdx.x) >> 6;
    if (node >= NN) return;
    agg_body(node, threadIdx.x, xh, start, deg, ebuf, a_src, a_dst, bias, gw, gb, hvb, gexpv, wlds);
}

// fast: all 3 views in one dispatch
__global__ __launch_bounds__(256) void aggregate3_kernel(const unsigned short* __restrict__ xh3,
                                                         const int* __restrict__ start3,
                                                         const int* __restrict__ deg3,
                                                         const unsigned int* __restrict__ ebuf3,
                                                         const float* __restrict__ a_src3,
                                                         const float* __restrict__ a_dst3,
                                                         const float* __restrict__ b0,
                                                         const float* __restrict__ b1,
                                                         const float* __restrict__ b2,
                                                         const float* __restrict__ gw,
                                                         const float* __restrict__ gb,
                                                         unsigned short* __restrict__ hvb3,
                                                         float* __restrict__ gexpv3) {
    __shared__ float wlds[4 * 260];
    int v = blockIdx.x / AGG_BLKS;
    int bin = blockIdx.x - v * AGG_BLKS;
    int node = (bin * 256 + threadIdx.x) >> 6;
    if (node >= NN) return;
    const float* bias = v == 0 ? b0 : v == 1 ? b1 : b2;
    agg_body(node, threadIdx.x,
             xh3 + (size_t)v * XH_ELEMS,
             start3 + v * NN, deg3 + v * NN,
             ebuf3 + (size_t)v * EPV,
             a_src3 + (size_t)v * A_ELEMS, a_dst3 + (size_t)v * A_ELEMS,
             bias, gw, gb,
             hvb3 + (size_t)v * HV_ELEMS, gexpv3 + v * NN, wlds);
}

// ================================================================ pool kernels
__global__ __launch_bounds__(1024) void pool_kernel(const unsigned short* __restrict__ hvb,
                                                    const float* __restrict__ gexpv,
                                                    const int* __restrict__ batch,
                                                    float* __restrict__ gout,
                                                    int voff) {
    __shared__ float sacc[8 * 128];
    __shared__ float sws[8];
    pool_body(blockIdx.x, threadIdx.x, hvb, gexpv, batch, gout, voff, sacc, sws);
}

__global__ __launch_bounds__(1024) void pool3_kernel(const unsigned short* __restrict__ hvb3,
                                                     const float* __restrict__ gexpv3,
                                                     const int* __restrict__ batch,
                                                     float* __restrict__ gout) {
    __shared__ float sacc[8 * 128];
    __shared__ float sws[8];
    int v = blockIdx.x >> 8;
    int b = blockIdx.x & 255;
    pool_body(b, threadIdx.x, hvb3 + (size_t)v * HV_ELEMS, gexpv3 + v * NN,
              batch, gout, v * 128, sacc, sws);
}

// ---------------------------------------------------------------- classifier
__global__ __launch_bounds__(128) void clf_kernel(const float* __restrict__ gout,
                                                  const float* __restrict__ W1,
                                                  const float* __restrict__ b1,
                                                  const float* __restrict__ W2,
                                                  const float* __restrict__ b2,
                                                  float* __restrict__ out) {
    int b = blockIdx.x;
    int j = threadIdx.x;
    float acc = b1[j];
    for (int k = 0; k < 384; k++) acc = fmaf(gout[b * 384 + k], W1[k * 128 + j], acc);
    acc = acc > 0.f ? acc : 0.01f * acc;
    float p = acc * W2[j];
    #pragma unroll
    for (int m = 1; m < 64; m <<= 1) p += __shfl_xor(p, m);
    __shared__ float sh[2];
    if ((j & 63) == 0) sh[j >> 6] = p;
    __syncthreads();
    if (j == 0) out[b] = sh[0] + sh[1] + b2[0];
}

// ---------------------------------------------------------------- launch
extern "C" void kernel_launch(void* const* d_in, const int* in_sizes, int n_in,
                              void* d_out, int out_size, void* d_ws, size_t ws_size,
                              hipStream_t stream) {
    const float* x      = (const float*)d_in[0];
    const int*   ei[3]  = {(const int*)d_in[1], (const int*)d_in[2], (const int*)d_in[3]};
    const int*   batch  = (const int*)d_in[4];
    const float* ln_g   = (const float*)d_in[5];
    const float* ln_b   = (const float*)d_in[6];
    const float* proj_W = (const float*)d_in[7];
    const float* proj_b = (const float*)d_in[8];
    const float* Wv[3]  = {(const float*)d_in[9],  (const float*)d_in[13], (const float*)d_in[17]};
    const float* asv[3] = {(const float*)d_in[10], (const float*)d_in[14], (const float*)d_in[18]};
    const float* adv[3] = {(const float*)d_in[11], (const float*)d_in[15], (const float*)d_in[19]};
    const float* bv[3]  = {(const float*)d_in[12], (const float*)d_in[16], (const float*)d_in[20]};
    const float* gate_W = (const float*)d_in[21];
    const float* gate_b = (const float*)d_in[22];
    const float* clf_W1 = (const float*)d_in[23];
    const float* clf_b1 = (const float*)d_in[24];
    const float* clf_W2 = (const float*)d_in[25];
    const float* clf_b2 = (const float*)d_in[26];
    float* out = (float*)d_out;

    (void)in_sizes; (void)n_in; (void)out_size;

    // ---- workspace layout (m = #replicated per-view buffers) ----
    char* base = (char*)d_ws;
    size_t off = 0;
    auto nxt = [&](size_t bytes) { char* r = base + off; off += (bytes + 255) & ~(size_t)255; return r; };

    unsigned short *h0, *xh, *hvb, *WT;
    float *c12, *a_src, *a_dst, *gexpv, *gout;
    int *deg3, *start3, *btot, *ebstart, *bstart, *blockHistT, *blockOffT;
    unsigned int *ebuf3, *pairbuf;

    auto layout = [&](int m) {
        off = 0;
        h0   = (unsigned short*)nxt((size_t)ROWS_PAD * 128 * 2);        // bf16
        xh   = (unsigned short*)nxt((size_t)m * XH_ELEMS * 2);          // fp16
        hvb  = (unsigned short*)nxt((size_t)m * HV_ELEMS * 2);          // fp16
        WT   = (unsigned short*)nxt(4 * 16384 * 2);
        c12    = (float*)nxt(256 * 4);
        a_src  = (float*)nxt((size_t)m * A_ELEMS * 4);
        a_dst  = (float*)nxt((size_t)m * A_ELEMS * 4);
        gexpv  = (float*)nxt((size_t)m * NN * 4);
        gout   = (float*)nxt(BB * 384 * 4);
        deg3   = (int*)nxt(3 * NN * 4);
        start3 = (int*)nxt(3 * NN * 4);
        ebuf3  = (unsigned int*)nxt(((size_t)3 * EPV + 64) * 4);
        btot   = (int*)nxt(3 * NBUCK * 4);
        ebstart = (int*)nxt(3 * (NBUCK + 1) * 4);
        bstart  = (int*)nxt(3 * (NBUCK + 1) * 4);
        blockHistT = (int*)nxt((size_t)NBUCK * TOTB * 4);
        blockOffT  = (int*)nxt((size_t)NBUCK * TOTB * 4);
        pairbuf = (unsigned int*)nxt((size_t)3 * EE * 4);
        return off;
    };

    size_t need_fast = layout(3);
    bool fast = (ws_size >= need_fast);
    if (!fast) layout(1);                     // fall back to proven single-buffer schedule

    // 1-2. weight packs + LN affine constants
    pack_wt<<<dim3(64, 4), 256, 0, stream>>>(proj_W, Wv[0], Wv[1], Wv[2], ln_g, WT);
    ln_consts<<<1, 512, 0, stream>>>(proj_W, ln_g, ln_b, c12);
    // 3. CSR histogram || proj GEMM (fused LN)
    fat_hist_proj<<<TOTB + GEMM_BLKS, 256, 0, stream>>>(ei[0], ei[1], ei[2], blockHistT,
                                                        x, WT, c12, proj_b, h0);
    // 4-6. bucket totals, starts, per-block offsets
    csr_bsum<<<(3 * NBUCK + 3) / 4, 256, 0, stream>>>(blockHistT, btot);
    csr_scan<<<3, 512, 0, stream>>>(btot, ebstart, bstart);
    csr_boff<<<(3 * NBUCK + 3) / 4, 256, 0, stream>>>(blockHistT, ebstart, blockOffT);

    if (fast) {
        // 7. coarse scatter || view GEMM x3
        fat_scatter_view3<<<TOTB + 3 * GEMM_BLKS, 256, 0, stream>>>(
            ei[0], ei[1], ei[2], blockOffT, pairbuf, h0, WT,
            asv[0], adv[0], asv[1], adv[1], asv[2], adv[2],
            xh, a_src, a_dst);
        // 8. fine sort (+self-loops)
        csr_fine<<<3 * NBUCK, 256, 0, stream>>>(pairbuf, btot, ebstart, bstart, deg3, start3, ebuf3);
        // 9. aggregate all views in one dispatch
        aggregate3_kernel<<<3 * AGG_BLKS, 256, 0, stream>>>(xh, start3, deg3, ebuf3,
                                                            a_src, a_dst,
                                                            bv[0], bv[1], bv[2],
                                                            gate_W, gate_b, hvb, gexpv);
        // 10. pool all views
        pool3_kernel<<<3 * 256, 1024, 0, stream>>>(hvb, gexpv, batch, gout);
    } else {
        // 7. coarse scatter || view-0 GEMM
        fat_scatter_view<<<TOTB + GEMM_BLKS, 256, 0, stream>>>(ei[0], ei[1], ei[2], blockOffT, pairbuf,
                                                               h0, WT, asv[0], adv[0], xh, a_src, a_dst);
        // 8. fine sort (+self-loops)
        csr_fine<<<3 * NBUCK, 256, 0, stream>>>(pairbuf, btot, ebstart, bstart, deg3, start3, ebuf3);
        // 9+. per view: (GEMM for v>0), aggregate, pool
        for (int v = 0; v < 3; v++) {
            if (v > 0)
                gemm_view<<<GEMM_BLKS, 256, 0, stream>>>(h0, WT + (size_t)(1 + v) * 16384,
                                                         asv[v], adv[v], xh, a_src, a_dst);
            aggregate_kernel<<<AGG_BLKS, 256, 0, stream>>>(xh, start3 + v * NN, deg3 + v * NN,
                                                           ebuf3 + (size_t)v * EPV,
                                                           a_src, a_dst,
                                                           bv[v], gate_W, gate_b, hvb, gexpv);
            pool_kernel<<<256, 1024, 0, stream>>>(hvb, gexpv, batch, gout, v * 128);
        }
    }
    // classifier
    clf_kernel<<<256, 128, 0, stream>>>(gout, clf_W1, clf_b1, clf_W2, clf_b2, out);
}